// Round 1
// baseline (1030.904 us; speedup 1.0000x reference)
//
#include <hip/hip_runtime.h>
#include <cstdint>

// SNN fused recurrence: B=1024 independent chains, T=512 sequential steps.
// One wave (64 lanes) per batch element; lane h owns hidden unit h.
// Layer 1: fp32 matvec, W1 row in VGPRs, x_t broadcast from LDS ring.
// Layers 2/3: spikes are binary + wave-uniform -> __ballot mask + sparse
// accumulation over set bits (wave-uniform loop, no divergence).

#define TT  512
#define DIN 128
#define HH  64
#define OO  20

__global__ __launch_bounds__(64, 1) void snn_fused(
    const float* __restrict__ x,      // (B, T, 128)
    const float* __restrict__ W1,     // (64, 128)
    const float* __restrict__ b1,
    const float* __restrict__ beta1,
    const float* __restrict__ W2,     // (64, 64)
    const float* __restrict__ b2,
    const float* __restrict__ beta2,
    const float* __restrict__ W3,     // (20, 64)
    const float* __restrict__ b3,
    const float* __restrict__ beta3,
    float* __restrict__ out)          // (B, T, 20)
{
    __shared__ float sW2T[HH * 65];   // sW2T[j*65+h] = W2[h][j]; stride 65 -> conflict-free
    __shared__ float sW3T[HH * 21];   // sW3T[j*21+o] = W3[o][j]; stride 21 -> conflict-free
    __shared__ float sx[8 * DIN];     // ring buffer: 8 timesteps of x

    const int lane = threadIdx.x;     // 0..63
    const int b    = blockIdx.x;      // batch element

    // ---- stage W1 row `lane` into registers (128 VGPRs, loaded once)
    float w1[DIN];
#pragma unroll
    for (int k = 0; k < DIN; k += 4) {
        const float4 v = *reinterpret_cast<const float4*>(W1 + lane * DIN + k);
        w1[k + 0] = v.x; w1[k + 1] = v.y; w1[k + 2] = v.z; w1[k + 3] = v.w;
    }

    // ---- stage W2^T: coalesced global read of row h, padded LDS write (bank-clean)
    for (int h = 0; h < HH; ++h) {
        sW2T[lane * 65 + h] = W2[h * HH + lane];      // position (j=lane, h)
    }
    // ---- stage W3^T
    for (int oo = 0; oo < OO; ++oo) {
        sW3T[lane * 21 + oo] = W3[oo * HH + lane];    // position (j=lane, o)
    }

    // ---- per-lane constants / state
    const float bb1 = b1[lane];
    const float bt1 = fminf(fmaxf(beta1[lane], 0.0f), 1.0f);
    const float bb2 = b2[lane];
    const float bt2 = fminf(fmaxf(beta2[lane], 0.0f), 1.0f);
    const int   o   = (lane < OO) ? lane : 0;
    const float bb3 = b3[o];
    const float bt3 = fminf(fmaxf(beta3[o], 0.0f), 1.0f);
    float m1 = 0.0f, m2 = 0.0f, m3 = 0.0f;

    const float* xb   = x   + (size_t)b * TT * DIN;
    float*       outb = out + (size_t)b * TT * OO;

    // ---- prefetch pipeline: issue 4 float4 loads (rows 0..7), write rows 0..3.
    // Each float4 load covers TWO timesteps per wave (1 KB coalesced).
    const float4 v0 = *reinterpret_cast<const float4*>(xb + 0 * DIN + 4 * lane); // rows 0,1
    const float4 v1 = *reinterpret_cast<const float4*>(xb + 2 * DIN + 4 * lane); // rows 2,3
    float4 pr = *reinterpret_cast<const float4*>(xb + 4 * DIN + 4 * lane);       // rows 4,5
    float4 pf = *reinterpret_cast<const float4*>(xb + 6 * DIN + 4 * lane);       // rows 6,7
    *reinterpret_cast<float4*>(sx + 0 * DIN + 4 * lane) = v0;
    *reinterpret_cast<float4*>(sx + 2 * DIN + 4 * lane) = v1;
    __syncthreads();

    for (int t = 0; t < TT; ++t) {
        // ---- layer 1: cur1 = dot(x_t, W1[lane,:]) + b1[lane]
        const float* xr = sx + (t & 7) * DIN;
        float a0 = 0.0f, a1 = 0.0f, a2 = 0.0f, a3 = 0.0f;
#pragma unroll
        for (int k = 0; k < DIN; k += 4) {
            const float4 xk = *reinterpret_cast<const float4*>(xr + k); // broadcast b128
            a0 = fmaf(xk.x, w1[k + 0], a0);
            a1 = fmaf(xk.y, w1[k + 1], a1);
            a2 = fmaf(xk.z, w1[k + 2], a2);
            a3 = fmaf(xk.w, w1[k + 3], a3);
        }
        const float cur1 = __fadd_rn(__fadd_rn(__fadd_rn(a0, a1), __fadd_rn(a2, a3)), bb1);
        // reset uses PREVIOUS membrane; update path matches numpy op-for-op (no fma contraction)
        const float r1 = (m1 > 1.0f) ? 1.0f : 0.0f;
        m1 = __fsub_rn(__fadd_rn(__fmul_rn(bt1, m1), cur1), r1);
        const unsigned long long s1 = __ballot(m1 > 1.0f);

        // ---- layer 2: sparse accumulate over spiking j (wave-uniform loop)
        float c2 = bb2;
        unsigned long long mm = s1;
        while (mm) {
            const int j = __builtin_ctzll(mm);
            mm &= (mm - 1);
            c2 = __fadd_rn(c2, sW2T[j * 65 + lane]);
        }
        const float r2 = (m2 > 1.0f) ? 1.0f : 0.0f;
        m2 = __fsub_rn(__fadd_rn(__fmul_rn(bt2, m2), c2), r2);
        const unsigned long long s2 = __ballot(m2 > 1.0f);

        // ---- layer 3 (no reset); lanes >= 20 compute harmlessly on o=0
        float c3 = bb3;
        mm = s2;
        while (mm) {
            const int j = __builtin_ctzll(mm);
            mm &= (mm - 1);
            c3 = __fadd_rn(c3, sW3T[j * 21 + o]);
        }
        m3 = __fadd_rn(__fmul_rn(bt3, m3), c3);
        if (lane < OO) outb[t * OO + lane] = m3;

        // ---- prefetch: even steps write rows t+4,t+5 (loaded 2 steps ago = ~2*step
        // latency in flight), then issue load of rows t+8,t+9.
        if (((t & 1) == 0) && (t + 4 < TT)) {
            *reinterpret_cast<float4*>(sx + ((t + 4) & 7) * DIN + 4 * lane) = pr;
            pr = pf;
            if (t + 8 < TT) {
                pf = *reinterpret_cast<const float4*>(xb + (t + 8) * DIN + 4 * lane);
            }
        }
        __syncthreads();
    }
}

extern "C" void kernel_launch(void* const* d_in, const int* in_sizes, int n_in,
                              void* d_out, int out_size, void* d_ws, size_t ws_size,
                              hipStream_t stream) {
    const float* x     = (const float*)d_in[0];
    const float* W1    = (const float*)d_in[1];
    const float* b1    = (const float*)d_in[2];
    const float* beta1 = (const float*)d_in[3];
    const float* W2    = (const float*)d_in[4];
    const float* b2    = (const float*)d_in[5];
    const float* beta2 = (const float*)d_in[6];
    const float* W3    = (const float*)d_in[7];
    const float* b3    = (const float*)d_in[8];
    const float* beta3 = (const float*)d_in[9];

    const int B = in_sizes[0] / (TT * DIN);   // 1024

    snn_fused<<<dim3(B), dim3(64), 0, stream>>>(
        x, W1, b1, beta1, W2, b2, beta2, W3, b3, beta3, (float*)d_out);
}

// Round 2
// 810.225 us; speedup vs baseline: 1.2724x; 1.2724x over previous
//
#include <hip/hip_runtime.h>
#include <cstdint>

// SNN fused recurrence: B=1024 independent chains, T=512 sequential steps.
// One wave (64 lanes) per batch element; lane h owns hidden unit h.
// Layer 1: fp32 matvec, W1 row in VGPRs, x_t broadcast from LDS ring.
// Layers 2/3: spikes are binary + wave-uniform -> __ballot mask + sparse
// accumulation over set bits, 2-stage software-pipelined LDS reads.
//
// R1 -> R2: removed ALL __syncthreads (block == 1 wave; intra-wave LDS
// ordering is handled by compiler lgkmcnt waits). The per-step barrier was
// draining vmcnt(0) — putting full HBM latency of the just-issued prefetch
// on the critical path every other step.

#define TT  512
#define DIN 128
#define HH  64
#define OO  20

__global__ __launch_bounds__(64, 1) void snn_fused(
    const float* __restrict__ x,      // (B, T, 128)
    const float* __restrict__ W1,     // (64, 128)
    const float* __restrict__ b1,
    const float* __restrict__ beta1,
    const float* __restrict__ W2,     // (64, 64)
    const float* __restrict__ b2,
    const float* __restrict__ beta2,
    const float* __restrict__ W3,     // (20, 64)
    const float* __restrict__ b3,
    const float* __restrict__ beta3,
    float* __restrict__ out)          // (B, T, 20)
{
    __shared__ float sW2T[HH * 65];   // sW2T[j*65+h] = W2[h][j]; stride 65 -> conflict-free
    __shared__ float sW3T[HH * 21];   // sW3T[j*21+o] = W3[o][j]; stride 21 -> conflict-free
    __shared__ float sx[8 * DIN];     // ring buffer: 8 timesteps of x

    const int lane = threadIdx.x;     // 0..63
    const int b    = blockIdx.x;      // batch element

    // ---- stage W1 row `lane` into registers (128 regs, loaded once)
    float w1[DIN];
#pragma unroll
    for (int k = 0; k < DIN; k += 4) {
        const float4 v = *reinterpret_cast<const float4*>(W1 + lane * DIN + k);
        w1[k + 0] = v.x; w1[k + 1] = v.y; w1[k + 2] = v.z; w1[k + 3] = v.w;
    }

    // ---- stage W2^T: coalesced global read of row h, padded LDS write (bank-clean)
    for (int h = 0; h < HH; ++h) {
        sW2T[lane * 65 + h] = W2[h * HH + lane];      // position (j=lane, h)
    }
    // ---- stage W3^T
    for (int oo = 0; oo < OO; ++oo) {
        sW3T[lane * 21 + oo] = W3[oo * HH + lane];    // position (j=lane, o)
    }

    // ---- per-lane constants / state
    const float bb1 = b1[lane];
    const float bt1 = fminf(fmaxf(beta1[lane], 0.0f), 1.0f);
    const float bb2 = b2[lane];
    const float bt2 = fminf(fmaxf(beta2[lane], 0.0f), 1.0f);
    const int   o   = (lane < OO) ? lane : 0;
    const float bb3 = b3[o];
    const float bt3 = fminf(fmaxf(beta3[o], 0.0f), 1.0f);
    float m1 = 0.0f, m2 = 0.0f, m3 = 0.0f;

    const float* xb   = x   + (size_t)b * TT * DIN;
    float*       outb = out + (size_t)b * TT * OO;

    const float* sW2row = sW2T + lane;   // + j*65
    const float* sW3row = sW3T + o;      // + j*21

    // ---- prefetch pipeline: rows 0..7 in flight / staged.
    // Each float4 load covers TWO timesteps per wave (1 KB coalesced).
    const float4 v0 = *reinterpret_cast<const float4*>(xb + 0 * DIN + 4 * lane); // rows 0,1
    const float4 v1 = *reinterpret_cast<const float4*>(xb + 2 * DIN + 4 * lane); // rows 2,3
    float4 pr = *reinterpret_cast<const float4*>(xb + 4 * DIN + 4 * lane);       // rows 4,5
    float4 pf = *reinterpret_cast<const float4*>(xb + 6 * DIN + 4 * lane);       // rows 6,7
    *reinterpret_cast<float4*>(sx + 0 * DIN + 4 * lane) = v0;
    *reinterpret_cast<float4*>(sx + 2 * DIN + 4 * lane) = v1;
    // NOTE: no __syncthreads anywhere — block is a single wave; LDS ordering
    // within a wave is guaranteed by compiler-inserted lgkmcnt waits.

    for (int t = 0; t < TT; ++t) {
        // ---- layer 1: cur1 = dot(x_t, W1[lane,:]) + b1[lane]
        // Summation structure (4 accumulators, stride 4, combine (a0+a1)+(a2+a3))
        // kept byte-identical to R1 — it matched the numpy reference exactly.
        const float* xr = sx + (t & 7) * DIN;
        float a0 = 0.0f, a1 = 0.0f, a2 = 0.0f, a3 = 0.0f;
#pragma unroll
        for (int k = 0; k < DIN; k += 4) {
            const float4 xk = *reinterpret_cast<const float4*>(xr + k); // broadcast b128
            a0 = fmaf(xk.x, w1[k + 0], a0);
            a1 = fmaf(xk.y, w1[k + 1], a1);
            a2 = fmaf(xk.z, w1[k + 2], a2);
            a3 = fmaf(xk.w, w1[k + 3], a3);
        }
        const float cur1 = __fadd_rn(__fadd_rn(__fadd_rn(a0, a1), __fadd_rn(a2, a3)), bb1);
        // reset uses PREVIOUS membrane; update path matches numpy op-for-op
        const float r1 = (m1 > 1.0f) ? 1.0f : 0.0f;
        m1 = __fsub_rn(__fadd_rn(__fmul_rn(bt1, m1), cur1), r1);
        const unsigned long long s1 = __ballot(m1 > 1.0f);

        // ---- layer 2: sparse accumulate, 2-stage pipelined (ascending j order)
        float c2 = bb2;
        {
            unsigned long long mm = s1;
            if (mm) {
                int j = __builtin_ctzll(mm); mm &= (mm - 1);
                float v = sW2row[j * 65];            // stage-A load
                while (mm) {
                    const int j2 = __builtin_ctzll(mm); mm &= (mm - 1);
                    const float v2 = sW2row[j2 * 65]; // stage-B load issued before A consumed
                    c2 = __fadd_rn(c2, v);
                    v = v2;
                }
                c2 = __fadd_rn(c2, v);
            }
        }
        const float r2 = (m2 > 1.0f) ? 1.0f : 0.0f;
        m2 = __fsub_rn(__fadd_rn(__fmul_rn(bt2, m2), c2), r2);
        const unsigned long long s2 = __ballot(m2 > 1.0f);

        // ---- layer 3 (no reset); s2 is almost always the zero mask -> fast skip
        float c3 = bb3;
        if (s2) {
            unsigned long long mm = s2;
            int j = __builtin_ctzll(mm); mm &= (mm - 1);
            float v = sW3row[j * 21];
            while (mm) {
                const int j2 = __builtin_ctzll(mm); mm &= (mm - 1);
                const float v2 = sW3row[j2 * 21];
                c3 = __fadd_rn(c3, v);
                v = v2;
            }
            c3 = __fadd_rn(c3, v);
        }
        m3 = __fadd_rn(__fmul_rn(bt3, m3), c3);
        if (lane < OO) outb[t * OO + lane] = m3;

        // ---- prefetch: even steps write rows t+4,t+5 (loaded ~4 steps ago ->
        // vmcnt wait fully covered), then issue load of rows t+8,t+9.
        if (((t & 1) == 0) && (t + 4 < TT)) {
            *reinterpret_cast<float4*>(sx + ((t + 4) & 7) * DIN + 4 * lane) = pr;
            pr = pf;
            if (t + 8 < TT) {
                pf = *reinterpret_cast<const float4*>(xb + (t + 8) * DIN + 4 * lane);
            }
        }
    }
}

extern "C" void kernel_launch(void* const* d_in, const int* in_sizes, int n_in,
                              void* d_out, int out_size, void* d_ws, size_t ws_size,
                              hipStream_t stream) {
    const float* x     = (const float*)d_in[0];
    const float* W1    = (const float*)d_in[1];
    const float* b1    = (const float*)d_in[2];
    const float* beta1 = (const float*)d_in[3];
    const float* W2    = (const float*)d_in[4];
    const float* b2    = (const float*)d_in[5];
    const float* beta2 = (const float*)d_in[6];
    const float* W3    = (const float*)d_in[7];
    const float* b3    = (const float*)d_in[8];
    const float* beta3 = (const float*)d_in[9];

    const int B = in_sizes[0] / (TT * DIN);   // 1024

    snn_fused<<<dim3(B), dim3(64), 0, stream>>>(
        x, W1, b1, beta1, W2, b2, beta2, W3, b3, beta3, (float*)d_out);
}